// Round 7
// baseline (128.675 us; speedup 1.0000x reference)
//
#include <hip/hip_runtime.h>

// edgeNet, round 7 (= r6 with the pkrtz type fix).
//   a1[n] = relu(feat[n]@W_nb  + b_nb ) @ W_att1[:128] + b_att1
//   a2[n] = relu(feat[n]@W_self+ b_self) @ W_att1[128:]
//   out[e] = relu(a1[e0] + a2[e1]) . W_att2 + b_att2
//
//  - node: stage-1 B-fragments (features) loaded DIRECTLY from global —
//    for the swapped product, lane (m,q) needs feat[node][kc*32+q*8..+8],
//    i.e. two contiguous float4. No Abuf, one barrier. LDS 32 KB.
//    Packing via v_cvt_pkrtz (1 instr per f16 pair; RTZ on features only).
//  - edge: 8 edges/thread (16 gathers in flight), consecutive-edge groups,
//    out written as two coalesced float4 per group.

#define N_NODES 50000
#define D_FEAT  128
#define H1      128
#define H2      64
#define N_EDGES 600000

typedef unsigned short u16;
typedef _Float16 f16;
typedef __attribute__((ext_vector_type(8))) _Float16 f16x8;
typedef __attribute__((ext_vector_type(2))) _Float16 f16x2;
typedef __attribute__((ext_vector_type(2))) __fp16 fp16x2_b;   // builtin ret type
typedef __attribute__((ext_vector_type(2))) float f32x2;
typedef __attribute__((ext_vector_type(4))) float f32x4;

union FragH { uint4 u; f16x8 v; };
union H2U   { unsigned u; f16x2 h; };

static __device__ __forceinline__ u16 f2h(float f) {
    union { f16 h; u16 u; } v; v.h = (f16)f; return v.u;   // v_cvt_f16_f32, RTN
}
static __device__ __forceinline__ unsigned hpack(float a, float b) {
    return (unsigned)f2h(a) | ((unsigned)f2h(b) << 16);
}
static __device__ __forceinline__ unsigned pkrtz(float a, float b) {
    union { fp16x2_b h; unsigned u; } v;
    v.h = __builtin_amdgcn_cvt_pkrtz(a, b);                // 1 instr, RTZ
    return v.u;
}

// ---------------------------------------------------------------------------
// prep: pack W1 = [Wnb | Wsf] (128x128 each) and Wat1 (256x64) into f16
// fragment-major layouts (RTN rounding for weights).
//   W1F slot ((cs*4 + kc)*64 + q*16 + m)*8 + j  = W1[k = kc*32+q*8+j][col = cs*16+m]
//   W2F slot ((cs2*8 + kc)*64 + q*16 + m)*8 + j = Wat1[k = kc*32+q*8+j][col2 = cs2*16+m]
// ---------------------------------------------------------------------------
__global__ __launch_bounds__(256) void prep_kernel(
    const float* __restrict__ Wnb, const float* __restrict__ Wsf,
    const float* __restrict__ Wat1,
    u16* __restrict__ W1F, u16* __restrict__ W2F)
{
    const int t = threadIdx.x;
    const int b = blockIdx.x;
    if (b < 16) {
        const int cs = b;
        const int kc = t >> 6, q = (t >> 4) & 3, m = t & 15;
        const int col = cs * 16 + m;
        const float* src = (col < H1) ? (Wnb + col) : (Wsf + (col - H1));
        const int k0 = kc * 32 + q * 8;
        float e[8];
        #pragma unroll
        for (int j = 0; j < 8; ++j) e[j] = src[(size_t)(k0 + j) * H1];
        uint4 pk = make_uint4(hpack(e[0], e[1]), hpack(e[2], e[3]),
                              hpack(e[4], e[5]), hpack(e[6], e[7]));
        *((uint4*)&W1F[((cs * 4 + kc) * 64 + q * 16 + m) * 8]) = pk;
    } else {
        for (int i = t; i < 4 * 8 * 64; i += 256) {
            const int lane = i & 63, pair = i >> 6;          // pair = cs2*8 + kc
            const int q = lane >> 4, m = lane & 15;
            const int cs2 = pair >> 3, kc = pair & 7;
            const int col2 = cs2 * 16 + m;
            const int k0 = kc * 32 + q * 8;
            float e[8];
            #pragma unroll
            for (int j = 0; j < 8; ++j) e[j] = Wat1[(size_t)(k0 + j) * H2 + col2];
            uint4 pk = make_uint4(hpack(e[0], e[1]), hpack(e[2], e[3]),
                                  hpack(e[4], e[5]), hpack(e[6], e[7]));
            *((uint4*)&W2F[(pair * 64 + lane) * 8]) = pk;
        }
    }
}

// ---------------------------------------------------------------------------
// node kernel: 64 nodes/block, 4 waves, f16 MFMA 16x16x32.
// Stage 1 swapped: D' = W1^T * F^T, F^T fragments straight from global.
// Stage 2 swapped: D' = W2^T * H^T via Hbuf (only LDS buffer, one barrier).
// ---------------------------------------------------------------------------
__global__ __launch_bounds__(256) void node_kernel(
    const float* __restrict__ feat,
    const u16* __restrict__ W1F,  const u16* __restrict__ W2F,
    const float* __restrict__ bnb,  const float* __restrict__ bsf,
    const float* __restrict__ bat1,
    u16* __restrict__ a1, u16* __restrict__ a2)
{
    __shared__ u16 Hbuf[4 * 8 * 64 * 8];   // hidden, frag-major (32 KB)

    const int t    = threadIdx.x;
    const int w    = t >> 6;
    const int lane = t & 63;
    const int m    = lane & 15;
    const int q    = lane >> 4;
    const int n0   = blockIdx.x * 64;

    // ---- weight fragments: coalesced uint4 loads from frag-major buffer ----
    FragH w1f[4][4];
    #pragma unroll
    for (int ms = 0; ms < 4; ++ms)
        #pragma unroll
        for (int kc = 0; kc < 4; ++kc)
            w1f[ms][kc].u = *((const uint4*)&W1F[(((w * 4 + ms) * 4 + kc) * 64 + lane) * 8]);

    f32x4 acc1[4][4];
    #pragma unroll
    for (int i = 0; i < 4; ++i)
        #pragma unroll
        for (int j = 0; j < 4; ++j)
            acc1[i][j] = (f32x4){0.f, 0.f, 0.f, 0.f};

    // ---- stage 1 (swapped): B-frags of F^T direct from global ----
    #pragma unroll
    for (int kc = 0; kc < 4; ++kc) {
        const int koff = kc * 32 + q * 8;
        FragH ff[4];
        #pragma unroll
        for (int ns = 0; ns < 4; ++ns) {
            const int gn = n0 + ns * 16 + m;
            float4 va = make_float4(0.f,0.f,0.f,0.f), vb = va;
            if (gn < N_NODES) {
                const float* src = feat + (size_t)gn * D_FEAT + koff;
                va = ((const float4*)src)[0];
                vb = ((const float4*)src)[1];
            }
            ff[ns].u = make_uint4(pkrtz(va.x, va.y), pkrtz(va.z, va.w),
                                  pkrtz(vb.x, vb.y), pkrtz(vb.z, vb.w));
        }
        #pragma unroll
        for (int ns = 0; ns < 4; ++ns)
            #pragma unroll
            for (int ms = 0; ms < 4; ++ms)
                acc1[ms][ns] = __builtin_amdgcn_mfma_f32_16x16x32_f16(
                    w1f[ms][kc].v, ff[ns].v, acc1[ms][ns], 0, 0, 0);
    }

    // ---- epilogue 1: bias + relu, pack 4 consecutive h-cols -> Hbuf ----
    #pragma unroll
    for (int ms = 0; ms < 4; ++ms) {
        const int hcol0 = w * 64 + ms * 16 + q * 4;
        const float* bsrc = (hcol0 < H1) ? (bnb + hcol0) : (bsf + (hcol0 - H1));
        const float4 bb = *((const float4*)bsrc);
        const int kc2 = hcol0 >> 5;
        const int q2  = (hcol0 >> 3) & 3;
        const int j0  = hcol0 & 7;
        #pragma unroll
        for (int ns = 0; ns < 4; ++ns) {
            const f32x4 a = acc1[ms][ns];
            const float v0 = fmaxf(a.x + bb.x, 0.f);
            const float v1 = fmaxf(a.y + bb.y, 0.f);
            const float v2 = fmaxf(a.z + bb.z, 0.f);
            const float v3 = fmaxf(a.w + bb.w, 0.f);
            const int idx = ((ns * 8 + kc2) * 64 + (q2 * 16 + m)) * 8 + j0;
            uint2 p; p.x = hpack(v0, v1); p.y = hpack(v2, v3);
            *((uint2*)&Hbuf[idx]) = p;
        }
    }

    // ---- W2 fragments (coalesced) ----
    FragH w2f[2][4];
    #pragma unroll
    for (int ns2 = 0; ns2 < 2; ++ns2) {
        const int cs2 = (w & 1) * 2 + ns2;
        #pragma unroll
        for (int kcl = 0; kcl < 4; ++kcl) {
            const int kc = kcl + ((w < 2) ? 0 : 4);
            w2f[ns2][kcl].u = *((const uint4*)&W2F[((cs2 * 8 + kc) * 64 + lane) * 8]);
        }
    }

    f32x4 acc2[4][2];
    #pragma unroll
    for (int i = 0; i < 4; ++i) { acc2[i][0] = (f32x4){0.f,0.f,0.f,0.f};
                                  acc2[i][1] = (f32x4){0.f,0.f,0.f,0.f}; }

    __syncthreads();

    // ---- stage 2 (swapped): D' = W2^T * H^T ----
    #pragma unroll
    for (int kcl = 0; kcl < 4; ++kcl) {
        const int kc2 = kcl + ((w < 2) ? 0 : 4);   // h1 cols for a1, h2 for a2
        #pragma unroll
        for (int ms = 0; ms < 4; ++ms) {
            FragH hf; hf.u = *((const uint4*)&Hbuf[((ms * 8 + kc2) * 64 + lane) * 8]);
            #pragma unroll
            for (int ns2 = 0; ns2 < 2; ++ns2)
                acc2[ms][ns2] = __builtin_amdgcn_mfma_f32_16x16x32_f16(
                    w2f[ns2][kcl].v, hf.v, acc2[ms][ns2], 0, 0, 0);
        }
    }

    // ---- epilogue 2: 4 consecutive out-cols per lane -> ushort4 stores ----
    u16* aout = (w < 2) ? a1 : a2;
    const int colbase = (w & 1) * 32;
    #pragma unroll
    for (int ns2 = 0; ns2 < 2; ++ns2) {
        const int c0 = colbase + ns2 * 16 + q * 4;
        float4 b2 = make_float4(0.f, 0.f, 0.f, 0.f);
        if (w < 2) b2 = *((const float4*)(bat1 + c0));
        #pragma unroll
        for (int ms = 0; ms < 4; ++ms) {
            const int node = n0 + ms * 16 + m;
            if (node < N_NODES) {
                const f32x4 a = acc2[ms][ns2];
                ushort4 pk;
                pk.x = f2h(a.x + b2.x); pk.y = f2h(a.y + b2.y);
                pk.z = f2h(a.z + b2.z); pk.w = f2h(a.w + b2.w);
                *((ushort4*)(aout + (size_t)node * H2 + c0)) = pk;
            }
        }
    }
}

// ---------------------------------------------------------------------------
// edge kernel: 8 lanes/edge, 8 CONSECUTIVE edges/thread-group (16 gathers in
// flight per thread). Lane 0 of each group writes two coalesced float4.
// ---------------------------------------------------------------------------
static __device__ __forceinline__ float edot(uint4 a, uint4 b,
                                             float4 w0, float4 w1) {
    const f16x2 z = (f16x2)(f16)0;
    float s = 0.f;
    {
        H2U x, y; x.u = a.x; y.u = b.x;
        f16x2 r = __builtin_elementwise_max(x.h + y.h, z);
        f32x2 f = __builtin_convertvector(r, f32x2);
        s = fmaf(f.x, w0.x, fmaf(f.y, w0.y, s));
    }
    {
        H2U x, y; x.u = a.y; y.u = b.y;
        f16x2 r = __builtin_elementwise_max(x.h + y.h, z);
        f32x2 f = __builtin_convertvector(r, f32x2);
        s = fmaf(f.x, w0.z, fmaf(f.y, w0.w, s));
    }
    {
        H2U x, y; x.u = a.z; y.u = b.z;
        f16x2 r = __builtin_elementwise_max(x.h + y.h, z);
        f32x2 f = __builtin_convertvector(r, f32x2);
        s = fmaf(f.x, w1.x, fmaf(f.y, w1.y, s));
    }
    {
        H2U x, y; x.u = a.w; y.u = b.w;
        f16x2 r = __builtin_elementwise_max(x.h + y.h, z);
        f32x2 f = __builtin_convertvector(r, f32x2);
        s = fmaf(f.x, w1.z, fmaf(f.y, w1.w, s));
    }
    return s;
}

__global__ __launch_bounds__(256) void edge_kernel(
    const int* __restrict__ edges,
    const u16* __restrict__ a1, const u16* __restrict__ a2,
    const float* __restrict__ Wat2, const float* __restrict__ bat2,
    float* __restrict__ out)
{
    const int t = threadIdx.x;
    const int l = t & 7;
    const int g = t >> 3;                        // 0..31
    const int base = blockIdx.x * 256 + g * 8;   // 8 consecutive edges / group
    // N_EDGES % 8 == 0, so groups are all-full or all-empty.
    if (base >= N_EDGES) return;

    const float4 w0 = ((const float4*)Wat2)[l * 2 + 0];
    const float4 w1 = ((const float4*)Wat2)[l * 2 + 1];
    const float  bias = bat2[0];

    int2 ep[8];
    #pragma unroll
    for (int i = 0; i < 8; ++i)
        ep[i] = ((const int2*)edges)[base + i];

    uint4 q1[8], q2[8];
    #pragma unroll
    for (int i = 0; i < 8; ++i) {
        q1[i] = ((const uint4*)(a1 + (size_t)ep[i].x * H2))[l];
        q2[i] = ((const uint4*)(a2 + (size_t)ep[i].y * H2))[l];
    }

    float s[8];
    #pragma unroll
    for (int i = 0; i < 8; ++i) {
        s[i] = edot(q1[i], q2[i], w0, w1);
        s[i] += __shfl_down(s[i], 4, 8);
        s[i] += __shfl_down(s[i], 2, 8);
        s[i] += __shfl_down(s[i], 1, 8);
    }

    if (l == 0) {
        float4 o0 = make_float4(s[0]+bias, s[1]+bias, s[2]+bias, s[3]+bias);
        float4 o1 = make_float4(s[4]+bias, s[5]+bias, s[6]+bias, s[7]+bias);
        *((float4*)(out + base))     = o0;
        *((float4*)(out + base + 4)) = o1;
    }
}

extern "C" void kernel_launch(void* const* d_in, const int* in_sizes, int n_in,
                              void* d_out, int out_size, void* d_ws, size_t ws_size,
                              hipStream_t stream) {
    const float* feat  = (const float*)d_in[0];
    const int*   edges = (const int*)d_in[1];
    const float* Wnb   = (const float*)d_in[2];
    const float* bnb   = (const float*)d_in[3];
    const float* Wsf   = (const float*)d_in[4];
    const float* bsf   = (const float*)d_in[5];
    const float* Wat1  = (const float*)d_in[6];
    const float* bat1  = (const float*)d_in[7];
    const float* Wat2  = (const float*)d_in[8];
    const float* bat2  = (const float*)d_in[9];
    float* out = (float*)d_out;

    u16* a1  = (u16*)d_ws;                         // 6.4 MB (f16)
    u16* a2  = a1 + (size_t)N_NODES * H2;          // 6.4 MB
    u16* W1F = a2 + (size_t)N_NODES * H2;          // 64 KB
    u16* W2F = W1F + 16 * 4 * 64 * 8;              // 32 KB

    prep_kernel<<<17, 256, 0, stream>>>(Wnb, Wsf, Wat1, W1F, W2F);

    const int node_blocks = (N_NODES + 63) / 64;   // 782
    node_kernel<<<node_blocks, 256, 0, stream>>>(feat, W1F, W2F,
                                                 bnb, bsf, bat1, a1, a2);

    const int edge_blocks = (N_EDGES + 255) / 256; // 2344
    edge_kernel<<<edge_blocks, 256, 0, stream>>>(edges, a1, a2, Wat2, bat2, out);
}

// Round 8
// 120.433 us; speedup vs baseline: 1.0684x; 1.0684x over previous
//
#include <hip/hip_runtime.h>

// edgeNet, round 8 = r5 (best measured: 123.4 us) + consecutive-edge groups
// in the edge kernel (coalesced float4 out-stores). r6/r7's node
// direct-global-fragment experiment reverted (regressed: 4x redundant VMEM).
//   a1[n] = relu(feat[n]@W_nb  + b_nb ) @ W_att1[:128] + b_att1
//   a2[n] = relu(feat[n]@W_self+ b_self) @ W_att1[128:]
//   out[e] = relu(a1[e0] + a2[e1]) . W_att2 + b_att2

#define N_NODES 50000
#define D_FEAT  128
#define H1      128
#define H2      64
#define N_EDGES 600000

typedef unsigned short u16;
typedef _Float16 f16;
typedef __attribute__((ext_vector_type(8))) _Float16 f16x8;
typedef __attribute__((ext_vector_type(2))) _Float16 f16x2;
typedef __attribute__((ext_vector_type(2))) float f32x2;
typedef __attribute__((ext_vector_type(4))) float f32x4;

union FragH { uint4 u; f16x8 v; };
union H2U   { unsigned u; f16x2 h; };

static __device__ __forceinline__ u16 f2h(float f) {
    union { f16 h; u16 u; } v; v.h = (f16)f; return v.u;   // v_cvt_f16_f32, RTN
}
static __device__ __forceinline__ unsigned hpack(float a, float b) {
    return (unsigned)f2h(a) | ((unsigned)f2h(b) << 16);
}

// ---------------------------------------------------------------------------
// prep: pack W1 = [Wnb | Wsf] (128x128 each) and Wat1 (256x64) into f16
// fragment-major layouts.
//   W1F slot ((cs*4 + kc)*64 + q*16 + m)*8 + j  = W1[k = kc*32+q*8+j][col = cs*16+m]
//   W2F slot ((cs2*8 + kc)*64 + q*16 + m)*8 + j = Wat1[k = kc*32+q*8+j][col2 = cs2*16+m]
// ---------------------------------------------------------------------------
__global__ __launch_bounds__(256) void prep_kernel(
    const float* __restrict__ Wnb, const float* __restrict__ Wsf,
    const float* __restrict__ Wat1,
    u16* __restrict__ W1F, u16* __restrict__ W2F)
{
    const int t = threadIdx.x;
    const int b = blockIdx.x;
    if (b < 16) {
        const int cs = b;
        const int kc = t >> 6, q = (t >> 4) & 3, m = t & 15;
        const int col = cs * 16 + m;
        const float* src = (col < H1) ? (Wnb + col) : (Wsf + (col - H1));
        const int k0 = kc * 32 + q * 8;
        float e[8];
        #pragma unroll
        for (int j = 0; j < 8; ++j) e[j] = src[(size_t)(k0 + j) * H1];
        uint4 pk = make_uint4(hpack(e[0], e[1]), hpack(e[2], e[3]),
                              hpack(e[4], e[5]), hpack(e[6], e[7]));
        *((uint4*)&W1F[((cs * 4 + kc) * 64 + q * 16 + m) * 8]) = pk;
    } else {
        for (int i = t; i < 4 * 8 * 64; i += 256) {
            const int lane = i & 63, pair = i >> 6;          // pair = cs2*8 + kc
            const int q = lane >> 4, m = lane & 15;
            const int cs2 = pair >> 3, kc = pair & 7;
            const int col2 = cs2 * 16 + m;
            const int k0 = kc * 32 + q * 8;
            float e[8];
            #pragma unroll
            for (int j = 0; j < 8; ++j) e[j] = Wat1[(size_t)(k0 + j) * H2 + col2];
            uint4 pk = make_uint4(hpack(e[0], e[1]), hpack(e[2], e[3]),
                                  hpack(e[4], e[5]), hpack(e[6], e[7]));
            *((uint4*)&W2F[(pair * 64 + lane) * 8]) = pk;
        }
    }
}

// ---------------------------------------------------------------------------
// node kernel: 64 nodes/block, 4 waves, f16 MFMA 16x16x32.
// Stage 1 swapped: D' = W1^T * F^T  (C/D rows = h-cols -> packed Hbuf writes).
// Stage 2 swapped: D' = W2^T * H^T  (C/D rows = out-cols -> ushort4 stores).
// ---------------------------------------------------------------------------
__global__ __launch_bounds__(256) void node_kernel(
    const float* __restrict__ feat,
    const u16* __restrict__ W1F,  const u16* __restrict__ W2F,
    const float* __restrict__ bnb,  const float* __restrict__ bsf,
    const float* __restrict__ bat1,
    u16* __restrict__ a1, u16* __restrict__ a2)
{
    __shared__ u16 Abuf[4 * 4 * 64 * 8];   // features, frag-major (16 KB)
    __shared__ u16 Hbuf[4 * 8 * 64 * 8];   // hidden,   frag-major (32 KB)

    const int t    = threadIdx.x;
    const int w    = t >> 6;
    const int lane = t & 63;
    const int m    = lane & 15;
    const int q    = lane >> 4;
    const int n0   = blockIdx.x * 64;

    // ---- stage features -> f16, one full frag slot per thread per iter ----
    // slot = ((it*4 + kc)*64 + q*16 + m) with kc = t>>6, q = (t>>4)&3, m = t&15.
    // Consecutive t -> consecutive slots -> lane-contiguous uint4 writes
    // (conflict-free). Thread reads feat[n0+it*16+m][kc*32+q*8 .. +8] (32 B).
    {
        const int kcs = t >> 6;
        const int k0  = kcs * 32 + q * 8;
        #pragma unroll
        for (int it = 0; it < 4; ++it) {
            const int gn = n0 + it * 16 + m;
            float4 va = make_float4(0.f,0.f,0.f,0.f), vb = va;
            if (gn < N_NODES) {
                const float* src = feat + (size_t)gn * D_FEAT + k0;
                va = *((const float4*)src);
                vb = *((const float4*)(src + 4));
            }
            uint4 pk = make_uint4(hpack(va.x, va.y), hpack(va.z, va.w),
                                  hpack(vb.x, vb.y), hpack(vb.z, vb.w));
            *((uint4*)&Abuf[(((it * 4 + kcs) * 64) + (t & 63)) * 8]) = pk;
        }
    }

    // ---- weight fragments: coalesced uint4 loads from frag-major buffers ----
    FragH w1f[4][4];
    #pragma unroll
    for (int ms = 0; ms < 4; ++ms)
        #pragma unroll
        for (int kc = 0; kc < 4; ++kc)
            w1f[ms][kc].u = *((const uint4*)&W1F[(((w * 4 + ms) * 4 + kc) * 64 + lane) * 8]);

    f32x4 acc1[4][4];
    #pragma unroll
    for (int i = 0; i < 4; ++i)
        #pragma unroll
        for (int j = 0; j < 4; ++j)
            acc1[i][j] = (f32x4){0.f, 0.f, 0.f, 0.f};

    __syncthreads();

    // ---- stage 1 (swapped): h-col x node tiles ----
    #pragma unroll
    for (int kc = 0; kc < 4; ++kc) {
        #pragma unroll
        for (int ns = 0; ns < 4; ++ns) {
            FragH ff; ff.u = *((const uint4*)&Abuf[((ns * 4 + kc) * 64 + lane) * 8]);
            #pragma unroll
            for (int ms = 0; ms < 4; ++ms)
                acc1[ms][ns] = __builtin_amdgcn_mfma_f32_16x16x32_f16(
                    w1f[ms][kc].v, ff.v, acc1[ms][ns], 0, 0, 0);
        }
    }

    // ---- epilogue 1: bias + relu, pack 4 consecutive h-cols -> Hbuf ----
    #pragma unroll
    for (int ms = 0; ms < 4; ++ms) {
        const int hcol0 = w * 64 + ms * 16 + q * 4;
        const float* bsrc = (hcol0 < H1) ? (bnb + hcol0) : (bsf + (hcol0 - H1));
        const float4 bb = *((const float4*)bsrc);
        const int kc2 = hcol0 >> 5;
        const int q2  = (hcol0 >> 3) & 3;
        const int j0  = hcol0 & 7;
        #pragma unroll
        for (int ns = 0; ns < 4; ++ns) {
            const f32x4 a = acc1[ms][ns];
            const float v0 = fmaxf(a.x + bb.x, 0.f);
            const float v1 = fmaxf(a.y + bb.y, 0.f);
            const float v2 = fmaxf(a.z + bb.z, 0.f);
            const float v3 = fmaxf(a.w + bb.w, 0.f);
            const int idx = ((ns * 8 + kc2) * 64 + (q2 * 16 + m)) * 8 + j0;
            uint2 p; p.x = hpack(v0, v1); p.y = hpack(v2, v3);
            *((uint2*)&Hbuf[idx]) = p;
        }
    }

    // ---- W2 fragments (coalesced) ----
    FragH w2f[2][4];
    #pragma unroll
    for (int ns2 = 0; ns2 < 2; ++ns2) {
        const int cs2 = (w & 1) * 2 + ns2;
        #pragma unroll
        for (int kcl = 0; kcl < 4; ++kcl) {
            const int kc = kcl + ((w < 2) ? 0 : 4);
            w2f[ns2][kcl].u = *((const uint4*)&W2F[((cs2 * 8 + kc) * 64 + lane) * 8]);
        }
    }

    f32x4 acc2[4][2];
    #pragma unroll
    for (int i = 0; i < 4; ++i) { acc2[i][0] = (f32x4){0.f,0.f,0.f,0.f};
                                  acc2[i][1] = (f32x4){0.f,0.f,0.f,0.f}; }

    __syncthreads();

    // ---- stage 2 (swapped): D' = W2^T * H^T ----
    #pragma unroll
    for (int kcl = 0; kcl < 4; ++kcl) {
        const int kc2 = kcl + ((w < 2) ? 0 : 4);   // h1 cols for a1, h2 for a2
        #pragma unroll
        for (int ms = 0; ms < 4; ++ms) {
            FragH hf; hf.u = *((const uint4*)&Hbuf[((ms * 8 + kc2) * 64 + lane) * 8]);
            #pragma unroll
            for (int ns2 = 0; ns2 < 2; ++ns2)
                acc2[ms][ns2] = __builtin_amdgcn_mfma_f32_16x16x32_f16(
                    w2f[ns2][kcl].v, hf.v, acc2[ms][ns2], 0, 0, 0);
        }
    }

    // ---- epilogue 2: 4 consecutive out-cols per lane -> ushort4 stores ----
    u16* aout = (w < 2) ? a1 : a2;
    const int colbase = (w & 1) * 32;
    #pragma unroll
    for (int ns2 = 0; ns2 < 2; ++ns2) {
        const int c0 = colbase + ns2 * 16 + q * 4;
        float4 b2 = make_float4(0.f, 0.f, 0.f, 0.f);
        if (w < 2) b2 = *((const float4*)(bat1 + c0));
        #pragma unroll
        for (int ms = 0; ms < 4; ++ms) {
            const int node = n0 + ms * 16 + m;
            if (node < N_NODES) {
                const f32x4 a = acc2[ms][ns2];
                ushort4 pk;
                pk.x = f2h(a.x + b2.x); pk.y = f2h(a.y + b2.y);
                pk.z = f2h(a.z + b2.z); pk.w = f2h(a.w + b2.w);
                *((ushort4*)(aout + (size_t)node * H2 + c0)) = pk;
            }
        }
    }
}

// ---------------------------------------------------------------------------
// edge kernel: 8 lanes/edge, 4 CONSECUTIVE edges per thread-group
// (8 gathers of 16B in flight; lane 0 stores one coalesced float4).
// ---------------------------------------------------------------------------
static __device__ __forceinline__ float edot(uint4 a, uint4 b,
                                             float4 w0, float4 w1) {
    const f16x2 z = (f16x2)(f16)0;
    float s = 0.f;
    {
        H2U x, y; x.u = a.x; y.u = b.x;
        f16x2 r = __builtin_elementwise_max(x.h + y.h, z);
        f32x2 f = __builtin_convertvector(r, f32x2);
        s = fmaf(f.x, w0.x, fmaf(f.y, w0.y, s));
    }
    {
        H2U x, y; x.u = a.y; y.u = b.y;
        f16x2 r = __builtin_elementwise_max(x.h + y.h, z);
        f32x2 f = __builtin_convertvector(r, f32x2);
        s = fmaf(f.x, w0.z, fmaf(f.y, w0.w, s));
    }
    {
        H2U x, y; x.u = a.z; y.u = b.z;
        f16x2 r = __builtin_elementwise_max(x.h + y.h, z);
        f32x2 f = __builtin_convertvector(r, f32x2);
        s = fmaf(f.x, w1.x, fmaf(f.y, w1.y, s));
    }
    {
        H2U x, y; x.u = a.w; y.u = b.w;
        f16x2 r = __builtin_elementwise_max(x.h + y.h, z);
        f32x2 f = __builtin_convertvector(r, f32x2);
        s = fmaf(f.x, w1.z, fmaf(f.y, w1.w, s));
    }
    return s;
}

__global__ __launch_bounds__(256) void edge_kernel(
    const int* __restrict__ edges,
    const u16* __restrict__ a1, const u16* __restrict__ a2,
    const float* __restrict__ Wat2, const float* __restrict__ bat2,
    float* __restrict__ out)
{
    const int t = threadIdx.x;
    const int l = t & 7;
    const int g = t >> 3;                        // 0..31
    const int base = blockIdx.x * 128 + g * 4;   // 4 consecutive edges / group
    // N_EDGES % 4 == 0 and groups are 4-aligned -> all-full or all-empty.
    if (base >= N_EDGES) return;

    const float4 w0 = ((const float4*)Wat2)[l * 2 + 0];
    const float4 w1 = ((const float4*)Wat2)[l * 2 + 1];
    const float  bias = bat2[0];

    int2 ep[4];
    #pragma unroll
    for (int i = 0; i < 4; ++i)
        ep[i] = ((const int2*)edges)[base + i];

    uint4 q1[4], q2[4];
    #pragma unroll
    for (int i = 0; i < 4; ++i) {
        q1[i] = ((const uint4*)(a1 + (size_t)ep[i].x * H2))[l];
        q2[i] = ((const uint4*)(a2 + (size_t)ep[i].y * H2))[l];
    }

    float s[4];
    #pragma unroll
    for (int i = 0; i < 4; ++i) {
        s[i] = edot(q1[i], q2[i], w0, w1);
        s[i] += __shfl_down(s[i], 4, 8);
        s[i] += __shfl_down(s[i], 2, 8);
        s[i] += __shfl_down(s[i], 1, 8);
    }

    if (l == 0) {
        float4 o = make_float4(s[0]+bias, s[1]+bias, s[2]+bias, s[3]+bias);
        *((float4*)(out + base)) = o;
    }
}

extern "C" void kernel_launch(void* const* d_in, const int* in_sizes, int n_in,
                              void* d_out, int out_size, void* d_ws, size_t ws_size,
                              hipStream_t stream) {
    const float* feat  = (const float*)d_in[0];
    const int*   edges = (const int*)d_in[1];
    const float* Wnb   = (const float*)d_in[2];
    const float* bnb   = (const float*)d_in[3];
    const float* Wsf   = (const float*)d_in[4];
    const float* bsf   = (const float*)d_in[5];
    const float* Wat1  = (const float*)d_in[6];
    const float* bat1  = (const float*)d_in[7];
    const float* Wat2  = (const float*)d_in[8];
    const float* bat2  = (const float*)d_in[9];
    float* out = (float*)d_out;

    u16* a1  = (u16*)d_ws;                         // 6.4 MB (f16)
    u16* a2  = a1 + (size_t)N_NODES * H2;          // 6.4 MB
    u16* W1F = a2 + (size_t)N_NODES * H2;          // 64 KB
    u16* W2F = W1F + 16 * 4 * 64 * 8;              // 32 KB

    prep_kernel<<<17, 256, 0, stream>>>(Wnb, Wsf, Wat1, W1F, W2F);

    const int node_blocks = (N_NODES + 63) / 64;   // 782
    node_kernel<<<node_blocks, 256, 0, stream>>>(feat, W1F, W2F,
                                                 bnb, bsf, bat1, a1, a2);

    const int edge_blocks = (N_EDGES + 127) / 128; // 4688
    edge_kernel<<<edge_blocks, 256, 0, stream>>>(edges, a1, a2, Wat2, bat2, out);
}